// Round 1
// baseline (383.620 us; speedup 1.0000x reference)
//
#include <hip/hip_runtime.h>
#include <math.h>

#define HW   4096
#define CIN  256
#define ICH  128
#define NB   4

typedef __attribute__((ext_vector_type(4))) float f32x4;
typedef __attribute__((ext_vector_type(8))) short bf16x8;

__device__ inline short f2bf(float f) {
    unsigned int u = __float_as_uint(f);
    u += 0x7fffU + ((u >> 16) & 1U);   // round-to-nearest-even
    return (short)(u >> 16);
}

__device__ inline f32x4 mfma16(bf16x8 a, bf16x8 b, f32x4 c) {
    return __builtin_amdgcn_mfma_f32_16x16x32_bf16(a, b, c, 0, 0, 0);
}

__device__ inline bf16x8 ldf(const short* p) { return *(const bf16x8*)p; }

// ---------------------------------------------------------------------------
// K0: convert weights to bf16, fold BN params.
// grid 128 x 256 threads; i covers 32768 = 128*256 elements of each matrix.
// bnp layout: [0..127]=a_th, [128..255]=b_th, [256..383]=a_ph, [384..511]=b_ph
// ---------------------------------------------------------------------------
__global__ void k_prep_w(const float* __restrict__ wth, const float* __restrict__ wph,
                         const float* __restrict__ wg,  const float* __restrict__ ww,
                         const float* __restrict__ gth, const float* __restrict__ bth,
                         const float* __restrict__ mth, const float* __restrict__ vth,
                         const float* __restrict__ gph, const float* __restrict__ bph,
                         const float* __restrict__ mph, const float* __restrict__ vph,
                         short* __restrict__ wthb, short* __restrict__ wphb,
                         short* __restrict__ wgb,  short* __restrict__ wwb,
                         float* __restrict__ bnp) {
    int i = blockIdx.x * 256 + threadIdx.x;
    wthb[i] = f2bf(wth[i]);
    wphb[i] = f2bf(wph[i]);
    wgb[i]  = f2bf(wg[i]);
    wwb[i]  = f2bf(ww[i]);
    if (blockIdx.x == 0 && threadIdx.x < ICH) {
        int o = threadIdx.x;
        float s1 = gth[o] * rsqrtf(vth[o] + 1e-5f);
        bnp[o]        = s1;
        bnp[ICH + o]  = bth[o] - mth[o] * s1;
        float s2 = gph[o] * rsqrtf(vph[o] + 1e-5f);
        bnp[2*ICH + o] = s2;
        bnp[3*ICH + o] = bph[o] - mph[o] * s2;
    }
}

// ---------------------------------------------------------------------------
// K1: x = max_d(feature), cx = feature[:, :, 5]; write transposed (n,q,c) bf16.
// grid (64 qtiles, 8 ctiles, 4 n), 256 threads.
// ---------------------------------------------------------------------------
__global__ __launch_bounds__(256) void k_prep_x(const float* __restrict__ feat,
                                                short* __restrict__ Xbf,
                                                short* __restrict__ CXbf) {
    const int q0 = blockIdx.x * 64;
    const int c0 = blockIdx.y * 32;
    const int n  = blockIdx.z;
    __shared__ float xs[32][65];
    __shared__ float cxs[32][65];
    const int lane = threadIdx.x & 63;
    const int cw   = threadIdx.x >> 6;      // 0..3

    #pragma unroll
    for (int i = 0; i < 8; ++i) {
        int c = c0 + cw * 8 + i;
        const float* fp = feat + ((long long)(n * CIN + c)) * 9 * HW + q0 + lane;
        float mx = fp[0];
        float cx = 0.f;
        #pragma unroll
        for (int d = 1; d < 9; ++d) {
            float v = fp[d * HW];
            if (d == 5) cx = v;
            mx = fmaxf(mx, v);
        }
        xs[cw * 8 + i][lane]  = mx;
        cxs[cw * 8 + i][lane] = cx;
    }
    __syncthreads();
    const int cc = threadIdx.x & 31;
    const int qq = threadIdx.x >> 5;        // 0..7
    #pragma unroll
    for (int k = 0; k < 8; ++k) {
        int q = qq * 8 + k;
        long long oidx = ((long long)(n * HW + q0 + q)) * CIN + c0 + cc;
        Xbf[oidx]  = f2bf(xs[cc][q]);
        CXbf[oidx] = f2bf(cxs[cc][q]);
    }
}

// ---------------------------------------------------------------------------
// K2: theta = relu(bn(Wth@cx)) (q,c), phi = relu(bn(Wph@x)) (q,c),
//     g computed with swapped MFMA roles -> Vt in (c,k) layout directly.
// grid (64, 4), 256 threads (4 waves x 16 q-rows).
// ---------------------------------------------------------------------------
__global__ __launch_bounds__(256) void k_conv3(const short* __restrict__ Xbf,
                                               const short* __restrict__ CXbf,
                                               const short* __restrict__ wthb,
                                               const short* __restrict__ wphb,
                                               const short* __restrict__ wgb,
                                               const float* __restrict__ bnp,
                                               short* __restrict__ theta,
                                               short* __restrict__ phi,
                                               short* __restrict__ Vt) {
    const int n    = blockIdx.y;
    const int wave = threadIdx.x >> 6;
    const int lane = threadIdx.x & 63;
    const int lr = lane & 15, lg = lane >> 4;
    const int q0 = blockIdx.x * 64 + wave * 16;
    const short* Xn  = Xbf  + (size_t)n * HW * CIN;
    const short* CXn = CXbf + (size_t)n * HW * CIN;
    short* thn = theta + (size_t)n * HW * ICH;
    short* phn = phi   + (size_t)n * HW * ICH;
    short* vtn = Vt    + (size_t)n * ICH * HW;

    // ---- theta: D[m=q, n=o], A = CX(q,c), B = Wth(o,c)
    f32x4 acc[8];
    #pragma unroll
    for (int i = 0; i < 8; ++i) { acc[i][0]=0.f; acc[i][1]=0.f; acc[i][2]=0.f; acc[i][3]=0.f; }
    #pragma unroll
    for (int cf = 0; cf < 8; ++cf) {
        bf16x8 a = ldf(CXn + (q0 + lr) * CIN + cf * 32 + lg * 8);
        #pragma unroll
        for (int of = 0; of < 8; ++of) {
            bf16x8 b = ldf(wthb + (of * 16 + lr) * CIN + cf * 32 + lg * 8);
            acc[of] = mfma16(a, b, acc[of]);
        }
    }
    #pragma unroll
    for (int of = 0; of < 8; ++of) {
        int o = of * 16 + lr;
        float sA = bnp[o], sB = bnp[ICH + o];
        #pragma unroll
        for (int r = 0; r < 4; ++r) {
            int q = q0 + lg * 4 + r;
            thn[q * ICH + o] = f2bf(fmaxf(acc[of][r] * sA + sB, 0.f));
        }
    }

    // ---- phi: same with X, Wph
    #pragma unroll
    for (int i = 0; i < 8; ++i) { acc[i][0]=0.f; acc[i][1]=0.f; acc[i][2]=0.f; acc[i][3]=0.f; }
    #pragma unroll
    for (int cf = 0; cf < 8; ++cf) {
        bf16x8 a = ldf(Xn + (q0 + lr) * CIN + cf * 32 + lg * 8);
        #pragma unroll
        for (int of = 0; of < 8; ++of) {
            bf16x8 b = ldf(wphb + (of * 16 + lr) * CIN + cf * 32 + lg * 8);
            acc[of] = mfma16(a, b, acc[of]);
        }
    }
    #pragma unroll
    for (int of = 0; of < 8; ++of) {
        int o = of * 16 + lr;
        float sA = bnp[2*ICH + o], sB = bnp[3*ICH + o];
        #pragma unroll
        for (int r = 0; r < 4; ++r) {
            int q = q0 + lg * 4 + r;
            phn[q * ICH + o] = f2bf(fmaxf(acc[of][r] * sA + sB, 0.f));
        }
    }

    // ---- g: D[m=o, n=q], A = Wg(o,c), B = X(q,c) -> store Vt[c][k] coalesced
    #pragma unroll
    for (int i = 0; i < 8; ++i) { acc[i][0]=0.f; acc[i][1]=0.f; acc[i][2]=0.f; acc[i][3]=0.f; }
    #pragma unroll
    for (int cf = 0; cf < 8; ++cf) {
        bf16x8 bx = ldf(Xn + (q0 + lr) * CIN + cf * 32 + lg * 8);
        #pragma unroll
        for (int mf = 0; mf < 8; ++mf) {
            bf16x8 a = ldf(wgb + (mf * 16 + lr) * CIN + cf * 32 + lg * 8);
            acc[mf] = mfma16(a, bx, acc[mf]);
        }
    }
    #pragma unroll
    for (int mf = 0; mf < 8; ++mf) {
        #pragma unroll
        for (int r = 0; r < 4; ++r) {
            int o = mf * 16 + lg * 4 + r;
            vtn[(size_t)o * HW + q0 + lr] = f2bf(acc[mf][r]);
        }
    }
}

// ---------------------------------------------------------------------------
// K3: flash attention. One wave per block, 16 q-rows per wave, KB=32 k-tiles.
// K/V read directly from global (L2-resident per batch). P bounced through a
// stride-80B LDS tile (≈2-way bank aliasing = free).
// grid 1024 x 64 threads. XCD-aware mapping: batch = (bid&7)>>1.
// ---------------------------------------------------------------------------
__global__ __launch_bounds__(64) void k_attn(const short* __restrict__ theta,
                                             const short* __restrict__ phi,
                                             const short* __restrict__ Vt,
                                             short* __restrict__ Obf) {
    const int bid = blockIdx.x;
    const int j = bid & 7;
    const int n = j >> 1;
    const int qtile = (bid >> 3) * 2 + (j & 1);
    const int q0 = qtile * 16;
    const int lane = threadIdx.x;
    const int lr = lane & 15, lg = lane >> 4;

    const short* Qn = theta + (size_t)n * HW * ICH;
    const short* Kn = phi   + (size_t)n * HW * ICH;
    const short* Vn = Vt    + (size_t)n * ICH * HW;
    short* On = Obf + (size_t)n * HW * ICH;

    __shared__ alignas(16) short plds[16 * 40];   // 16 rows x 32 k, 80B stride

    bf16x8 aq[4];
    #pragma unroll
    for (int cf = 0; cf < 4; ++cf)
        aq[cf] = ldf(Qn + (q0 + lr) * ICH + cf * 32 + lg * 8);

    f32x4 O[8];
    #pragma unroll
    for (int i = 0; i < 8; ++i) { O[i][0]=0.f; O[i][1]=0.f; O[i][2]=0.f; O[i][3]=0.f; }
    float m[4], l[4];
    #pragma unroll
    for (int r = 0; r < 4; ++r) { m[r] = -INFINITY; l[r] = 0.f; }

    for (int k0 = 0; k0 < HW; k0 += 32) {
        // S = Q K^T  (16q x 32k)
        f32x4 s0, s1;
        s0[0]=s0[1]=s0[2]=s0[3]=0.f;
        s1[0]=s1[1]=s1[2]=s1[3]=0.f;
        #pragma unroll
        for (int cf = 0; cf < 4; ++cf) {
            bf16x8 b0 = ldf(Kn + (k0 + lr) * ICH + cf * 32 + lg * 8);
            bf16x8 b1 = ldf(Kn + (k0 + 16 + lr) * ICH + cf * 32 + lg * 8);
            s0 = mfma16(aq[cf], b0, s0);
            s1 = mfma16(aq[cf], b1, s1);
        }
        // online softmax per q-row (rows lg*4+r, cols lr / 16+lr)
        float alpha[4];
        #pragma unroll
        for (int r = 0; r < 4; ++r) {
            float rmax = fmaxf(s0[r], s1[r]);
            rmax = fmaxf(rmax, __shfl_xor(rmax, 1));
            rmax = fmaxf(rmax, __shfl_xor(rmax, 2));
            rmax = fmaxf(rmax, __shfl_xor(rmax, 4));
            rmax = fmaxf(rmax, __shfl_xor(rmax, 8));
            float mnew = fmaxf(m[r], rmax);
            float p0 = __expf(s0[r] - mnew);
            float p1 = __expf(s1[r] - mnew);
            alpha[r] = __expf(m[r] - mnew);
            m[r] = mnew;
            float rs = p0 + p1;
            rs += __shfl_xor(rs, 1);
            rs += __shfl_xor(rs, 2);
            rs += __shfl_xor(rs, 4);
            rs += __shfl_xor(rs, 8);
            l[r] = l[r] * alpha[r] + rs;
            int row = lg * 4 + r;
            plds[row * 40 + lr]      = f2bf(p0);
            plds[row * 40 + 16 + lr] = f2bf(p1);
        }
        #pragma unroll
        for (int cc = 0; cc < 8; ++cc) {
            #pragma unroll
            for (int r = 0; r < 4; ++r) O[cc][r] *= alpha[r];
        }
        // P (16x32) as A-frag from LDS; O += P * V
        bf16x8 pa = ldf(plds + lr * 40 + lg * 8);
        #pragma unroll
        for (int cc = 0; cc < 8; ++cc) {
            bf16x8 bv = ldf(Vn + (size_t)(cc * 16 + lr) * HW + k0 + lg * 8);
            O[cc] = mfma16(pa, bv, O[cc]);
        }
    }
    #pragma unroll
    for (int r = 0; r < 4; ++r) l[r] = 1.0f / l[r];
    #pragma unroll
    for (int cc = 0; cc < 8; ++cc) {
        #pragma unroll
        for (int r = 0; r < 4; ++r) {
            int q = q0 + lg * 4 + r;
            int c = cc * 16 + lr;
            On[q * ICH + c] = f2bf(O[cc][r] * l[r]);
        }
    }
}

// ---------------------------------------------------------------------------
// K4: out[n,o,q] = sum_c ww[o,c]*O[q,c] + feature[n,o,5,q]
// D[m=o, n=q] so stores along q are coalesced. grid (64, 4), 256 threads.
// ---------------------------------------------------------------------------
__global__ __launch_bounds__(256) void k_out(const short* __restrict__ Obf,
                                             const short* __restrict__ wwb,
                                             const float* __restrict__ feat,
                                             float* __restrict__ out) {
    const int n    = blockIdx.y;
    const int wave = threadIdx.x >> 6;
    const int lane = threadIdx.x & 63;
    const int lr = lane & 15, lg = lane >> 4;
    const int q0 = blockIdx.x * 64;
    const int o0 = wave * 64;
    const short* On = Obf + (size_t)n * HW * ICH;

    f32x4 acc[4][4];
    #pragma unroll
    for (int i = 0; i < 4; ++i)
        #pragma unroll
        for (int jn = 0; jn < 4; ++jn) { acc[i][jn][0]=0.f; acc[i][jn][1]=0.f; acc[i][jn][2]=0.f; acc[i][jn][3]=0.f; }

    #pragma unroll
    for (int cf = 0; cf < 4; ++cf) {
        bf16x8 bO[4];
        #pragma unroll
        for (int nf = 0; nf < 4; ++nf)
            bO[nf] = ldf(On + (q0 + nf * 16 + lr) * ICH + cf * 32 + lg * 8);
        #pragma unroll
        for (int mf = 0; mf < 4; ++mf) {
            bf16x8 a = ldf(wwb + (o0 + mf * 16 + lr) * ICH + cf * 32 + lg * 8);
            #pragma unroll
            for (int nf = 0; nf < 4; ++nf)
                acc[mf][nf] = mfma16(a, bO[nf], acc[mf][nf]);
        }
    }
    #pragma unroll
    for (int mf = 0; mf < 4; ++mf) {
        #pragma unroll
        for (int nf = 0; nf < 4; ++nf) {
            #pragma unroll
            for (int r = 0; r < 4; ++r) {
                int o = o0 + mf * 16 + lg * 4 + r;
                int q = q0 + nf * 16 + lr;
                long long cxi = (((long long)(n * CIN + o)) * 9 + 5) * HW + q;
                out[((long long)(n * CIN + o)) * HW + q] = acc[mf][nf][r] + feat[cxi];
            }
        }
    }
}

// ---------------------------------------------------------------------------
extern "C" void kernel_launch(void* const* d_in, const int* in_sizes, int n_in,
                              void* d_out, int out_size, void* d_ws, size_t ws_size,
                              hipStream_t stream) {
    const float* feat = (const float*)d_in[0];
    const float* wth  = (const float*)d_in[1];
    const float* gth  = (const float*)d_in[2];
    const float* bth  = (const float*)d_in[3];
    const float* mth  = (const float*)d_in[4];
    const float* vth  = (const float*)d_in[5];
    const float* wph  = (const float*)d_in[6];
    const float* gph  = (const float*)d_in[7];
    const float* bph  = (const float*)d_in[8];
    const float* mph  = (const float*)d_in[9];
    const float* vph  = (const float*)d_in[10];
    const float* wg   = (const float*)d_in[11];
    const float* ww   = (const float*)d_in[12];
    float* out = (float*)d_out;

    size_t off = 0;
    auto carve = [&](size_t bytes) {
        void* p = (char*)d_ws + off;
        off += (bytes + 255) & ~(size_t)255;
        return p;
    };
    short* Xbf   = (short*)carve((size_t)NB * HW * CIN * 2);
    short* CXbf  = (short*)carve((size_t)NB * HW * CIN * 2);
    short* theta = (short*)carve((size_t)NB * HW * ICH * 2);
    short* phi   = (short*)carve((size_t)NB * HW * ICH * 2);
    short* Vt    = (short*)carve((size_t)NB * ICH * HW * 2);
    short* Obf   = (short*)carve((size_t)NB * HW * ICH * 2);
    short* wthb  = (short*)carve((size_t)ICH * CIN * 2);
    short* wphb  = (short*)carve((size_t)ICH * CIN * 2);
    short* wgb   = (short*)carve((size_t)ICH * CIN * 2);
    short* wwb   = (short*)carve((size_t)CIN * ICH * 2);
    float* bnp   = (float*)carve((size_t)4 * ICH * 4);

    k_prep_w<<<128, 256, 0, stream>>>(wth, wph, wg, ww, gth, bth, mth, vth,
                                      gph, bph, mph, vph, wthb, wphb, wgb, wwb, bnp);
    k_prep_x<<<dim3(64, 8, NB), 256, 0, stream>>>(feat, Xbf, CXbf);
    k_conv3<<<dim3(64, NB), 256, 0, stream>>>(Xbf, CXbf, wthb, wphb, wgb, bnp,
                                              theta, phi, Vt);
    k_attn<<<1024, 64, 0, stream>>>(theta, phi, Vt, Obf);
    k_out<<<dim3(64, NB), 256, 0, stream>>>(Obf, wwb, feat, out);
}

// Round 2
// 208.274 us; speedup vs baseline: 1.8419x; 1.8419x over previous
//
#include <hip/hip_runtime.h>
#include <math.h>

#define HW   4096
#define CIN  256
#define ICH  128
#define NB   4
#define KSPL 8

typedef __attribute__((ext_vector_type(4))) float f32x4;
typedef __attribute__((ext_vector_type(8))) short bf16x8;

typedef const __attribute__((address_space(1))) void* gptr_t;
typedef __attribute__((address_space(3))) void* lptr_t;

__device__ inline short f2bf(float f) {
    unsigned int u = __float_as_uint(f);
    u += 0x7fffU + ((u >> 16) & 1U);   // round-to-nearest-even
    return (short)(u >> 16);
}

__device__ inline float bf2f(short s) {
    return __uint_as_float(((unsigned int)(unsigned short)s) << 16);
}

__device__ inline f32x4 mfma16(bf16x8 a, bf16x8 b, f32x4 c) {
    return __builtin_amdgcn_mfma_f32_16x16x32_bf16(a, b, c, 0, 0, 0);
}

__device__ inline bf16x8 ldf(const short* p) { return *(const bf16x8*)p; }

// ---------------------------------------------------------------------------
// K0: convert weights to bf16, fold BN params.
// ---------------------------------------------------------------------------
__global__ void k_prep_w(const float* __restrict__ wth, const float* __restrict__ wph,
                         const float* __restrict__ wg,  const float* __restrict__ ww,
                         const float* __restrict__ gth, const float* __restrict__ bth,
                         const float* __restrict__ mth, const float* __restrict__ vth,
                         const float* __restrict__ gph, const float* __restrict__ bph,
                         const float* __restrict__ mph, const float* __restrict__ vph,
                         short* __restrict__ wthb, short* __restrict__ wphb,
                         short* __restrict__ wgb,  short* __restrict__ wwb,
                         float* __restrict__ bnp) {
    int i = blockIdx.x * 256 + threadIdx.x;
    wthb[i] = f2bf(wth[i]);
    wphb[i] = f2bf(wph[i]);
    wgb[i]  = f2bf(wg[i]);
    wwb[i]  = f2bf(ww[i]);
    if (blockIdx.x == 0 && threadIdx.x < ICH) {
        int o = threadIdx.x;
        float s1 = gth[o] * rsqrtf(vth[o] + 1e-5f);
        bnp[o]        = s1;
        bnp[ICH + o]  = bth[o] - mth[o] * s1;
        float s2 = gph[o] * rsqrtf(vph[o] + 1e-5f);
        bnp[2*ICH + o] = s2;
        bnp[3*ICH + o] = bph[o] - mph[o] * s2;
    }
}

// ---------------------------------------------------------------------------
// K1: x = max_d(feature), cx = feature[:, :, 5]; write transposed (n,q,c) bf16.
// ---------------------------------------------------------------------------
__global__ __launch_bounds__(256) void k_prep_x(const float* __restrict__ feat,
                                                short* __restrict__ Xbf,
                                                short* __restrict__ CXbf) {
    const int q0 = blockIdx.x * 64;
    const int c0 = blockIdx.y * 32;
    const int n  = blockIdx.z;
    __shared__ float xs[32][65];
    __shared__ float cxs[32][65];
    const int lane = threadIdx.x & 63;
    const int cw   = threadIdx.x >> 6;      // 0..3

    #pragma unroll
    for (int i = 0; i < 8; ++i) {
        int c = c0 + cw * 8 + i;
        const float* fp = feat + ((long long)(n * CIN + c)) * 9 * HW + q0 + lane;
        float mx = fp[0];
        float cx = 0.f;
        #pragma unroll
        for (int d = 1; d < 9; ++d) {
            float v = fp[d * HW];
            if (d == 5) cx = v;
            mx = fmaxf(mx, v);
        }
        xs[cw * 8 + i][lane]  = mx;
        cxs[cw * 8 + i][lane] = cx;
    }
    __syncthreads();
    const int cc = threadIdx.x & 31;
    const int qq = threadIdx.x >> 5;        // 0..7
    #pragma unroll
    for (int k = 0; k < 8; ++k) {
        int q = qq * 8 + k;
        long long oidx = ((long long)(n * HW + q0 + q)) * CIN + c0 + cc;
        Xbf[oidx]  = f2bf(xs[cc][q]);
        CXbf[oidx] = f2bf(cxs[cc][q]);
    }
}

// ---------------------------------------------------------------------------
// K2: theta/phi (q,c) with BN+ReLU; g with swapped roles -> Vt (c,k).
// ---------------------------------------------------------------------------
__global__ __launch_bounds__(256) void k_conv3(const short* __restrict__ Xbf,
                                               const short* __restrict__ CXbf,
                                               const short* __restrict__ wthb,
                                               const short* __restrict__ wphb,
                                               const short* __restrict__ wgb,
                                               const float* __restrict__ bnp,
                                               short* __restrict__ theta,
                                               short* __restrict__ phi,
                                               short* __restrict__ Vt) {
    const int n    = blockIdx.y;
    const int wave = threadIdx.x >> 6;
    const int lane = threadIdx.x & 63;
    const int lr = lane & 15, lg = lane >> 4;
    const int q0 = blockIdx.x * 64 + wave * 16;
    const short* Xn  = Xbf  + (size_t)n * HW * CIN;
    const short* CXn = CXbf + (size_t)n * HW * CIN;
    short* thn = theta + (size_t)n * HW * ICH;
    short* phn = phi   + (size_t)n * HW * ICH;
    short* vtn = Vt    + (size_t)n * ICH * HW;

    f32x4 acc[8];
    #pragma unroll
    for (int i = 0; i < 8; ++i) { acc[i][0]=0.f; acc[i][1]=0.f; acc[i][2]=0.f; acc[i][3]=0.f; }
    #pragma unroll
    for (int cf = 0; cf < 8; ++cf) {
        bf16x8 a = ldf(CXn + (q0 + lr) * CIN + cf * 32 + lg * 8);
        #pragma unroll
        for (int of = 0; of < 8; ++of) {
            bf16x8 b = ldf(wthb + (of * 16 + lr) * CIN + cf * 32 + lg * 8);
            acc[of] = mfma16(a, b, acc[of]);
        }
    }
    #pragma unroll
    for (int of = 0; of < 8; ++of) {
        int o = of * 16 + lr;
        float sA = bnp[o], sB = bnp[ICH + o];
        #pragma unroll
        for (int r = 0; r < 4; ++r) {
            int q = q0 + lg * 4 + r;
            thn[q * ICH + o] = f2bf(fmaxf(acc[of][r] * sA + sB, 0.f));
        }
    }

    #pragma unroll
    for (int i = 0; i < 8; ++i) { acc[i][0]=0.f; acc[i][1]=0.f; acc[i][2]=0.f; acc[i][3]=0.f; }
    #pragma unroll
    for (int cf = 0; cf < 8; ++cf) {
        bf16x8 a = ldf(Xn + (q0 + lr) * CIN + cf * 32 + lg * 8);
        #pragma unroll
        for (int of = 0; of < 8; ++of) {
            bf16x8 b = ldf(wphb + (of * 16 + lr) * CIN + cf * 32 + lg * 8);
            acc[of] = mfma16(a, b, acc[of]);
        }
    }
    #pragma unroll
    for (int of = 0; of < 8; ++of) {
        int o = of * 16 + lr;
        float sA = bnp[2*ICH + o], sB = bnp[3*ICH + o];
        #pragma unroll
        for (int r = 0; r < 4; ++r) {
            int q = q0 + lg * 4 + r;
            phn[q * ICH + o] = f2bf(fmaxf(acc[of][r] * sA + sB, 0.f));
        }
    }

    #pragma unroll
    for (int i = 0; i < 8; ++i) { acc[i][0]=0.f; acc[i][1]=0.f; acc[i][2]=0.f; acc[i][3]=0.f; }
    #pragma unroll
    for (int cf = 0; cf < 8; ++cf) {
        bf16x8 bx = ldf(Xn + (q0 + lr) * CIN + cf * 32 + lg * 8);
        #pragma unroll
        for (int mf = 0; mf < 8; ++mf) {
            bf16x8 a = ldf(wgb + (mf * 16 + lr) * CIN + cf * 32 + lg * 8);
            acc[mf] = mfma16(a, bx, acc[mf]);
        }
    }
    #pragma unroll
    for (int mf = 0; mf < 8; ++mf) {
        #pragma unroll
        for (int r = 0; r < 4; ++r) {
            int o = mf * 16 + lg * 4 + r;
            vtn[(size_t)o * HW + q0 + lr] = f2bf(acc[mf][r]);
        }
    }
}

// ---------------------------------------------------------------------------
// K3: flash attention, k-split x8 with bf16 partials + lse.
// Block = 4 waves x 32 q-rows = 128 q-rows, shared LDS K/V tile (64 keys).
// K/V staged via global_load_lds (linear LDS dest, inverse-swizzled global
// source); ds_reads apply the same XOR swizzle -> no 16-way bank conflicts.
// grid 1024 x 256. XCD mapping: batch n = (bid&7)>>1 (2 XCDs per batch,
// K+V per batch = 2MB fits 4MB XCD L2).
// ---------------------------------------------------------------------------
__global__ __launch_bounds__(256) void k_attn(const short* __restrict__ theta,
                                              const short* __restrict__ phi,
                                              const short* __restrict__ Vt,
                                              short* __restrict__ Op,
                                              float* __restrict__ Ls) {
    __shared__ char K_lds[16384];          // 64 keys x 128 ch bf16 (swizzled)
    __shared__ char V_lds[16384];          // 128 ch x 64 keys bf16 (swizzled)
    __shared__ short P_lds[4][32 * 72];    // per-wave P tile, stride 72 shorts

    const int bid  = blockIdx.x;
    const int j    = bid & 7;
    const int n    = j >> 1;
    const int rest = ((bid >> 3) << 1) | (j & 1);   // 0..255
    const int qb   = rest >> 3;                     // 0..31
    const int ks   = rest & 7;                      // 0..7
    const int wave = threadIdx.x >> 6;
    const int lane = threadIdx.x & 63;
    const int lr = lane & 15, lg = lane >> 4;
    const int q0 = qb * 128 + wave * 32;

    const short* Qn = theta + (size_t)n * HW * ICH;
    const short* Kn = phi   + (size_t)n * HW * ICH;
    const short* Vn = Vt    + (size_t)n * ICH * HW;

    bf16x8 aq[2][4];
    #pragma unroll
    for (int m2 = 0; m2 < 2; ++m2)
        #pragma unroll
        for (int cf = 0; cf < 4; ++cf)
            aq[m2][cf] = ldf(Qn + (q0 + m2 * 16 + lr) * ICH + cf * 32 + lg * 8);

    f32x4 O[2][8];
    #pragma unroll
    for (int m2 = 0; m2 < 2; ++m2)
        #pragma unroll
        for (int i = 0; i < 8; ++i) { O[m2][i][0]=0.f; O[m2][i][1]=0.f; O[m2][i][2]=0.f; O[m2][i][3]=0.f; }
    float mx[2][4], l[2][4];
    #pragma unroll
    for (int m2 = 0; m2 < 2; ++m2)
        #pragma unroll
        for (int r = 0; r < 4; ++r) { mx[m2][r] = -INFINITY; l[m2][r] = 0.f; }

    for (int t = 0; t < 8; ++t) {
        const int k0 = ks * 512 + t * 64;
        __syncthreads();   // all waves done reading previous tile
        #pragma unroll
        for (int i = 0; i < 4; ++i) {
            const int chunk = wave * 4 + i;
            const int o = chunk * 1024 + lane * 16;   // linear dest byte
            {   // K: LDS[row][colb ^ ((row&7)<<4)] = K[k0+row][colb]
                const int row = o >> 8;
                const int cb  = (o & 255) ^ ((row & 7) << 4);
                const char* src = (const char*)Kn + (size_t)(k0 + row) * 256 + cb;
                __builtin_amdgcn_global_load_lds((gptr_t)src, (lptr_t)(K_lds + chunk * 1024), 16, 0, 0);
            }
            {   // V: LDS[c][kb ^ ((c&7)<<4)] = V[c][k0*2 + kb]
                const int c  = o >> 7;
                const int kb = (o & 127) ^ ((c & 7) << 4);
                const char* src = (const char*)Vn + (size_t)c * (HW * 2) + (size_t)k0 * 2 + kb;
                __builtin_amdgcn_global_load_lds((gptr_t)src, (lptr_t)(V_lds + chunk * 1024), 16, 0, 0);
            }
        }
        __syncthreads();   // staged tile visible (vmcnt drained by barrier)

        // ---- S = Q K^T : 16 ds_reads, 32 MFMA
        f32x4 s[2][4];
        #pragma unroll
        for (int m2 = 0; m2 < 2; ++m2)
            #pragma unroll
            for (int tt = 0; tt < 4; ++tt) { s[m2][tt][0]=0.f; s[m2][tt][1]=0.f; s[m2][tt][2]=0.f; s[m2][tt][3]=0.f; }
        #pragma unroll
        for (int tt = 0; tt < 4; ++tt) {
            const int row = tt * 16 + lr;
            const int rsw = (row & 7) << 4;
            #pragma unroll
            for (int cf = 0; cf < 4; ++cf) {
                bf16x8 kf = *(const bf16x8*)(K_lds + row * 256 + ((cf * 64 + lg * 16) ^ rsw));
                s[0][tt] = mfma16(aq[0][cf], kf, s[0][tt]);
                s[1][tt] = mfma16(aq[1][cf], kf, s[1][tt]);
            }
        }

        // ---- online softmax with defer-max (THR=8)
        float rmax[2][4];
        int need = 0;
        #pragma unroll
        for (int m2 = 0; m2 < 2; ++m2)
            #pragma unroll
            for (int r = 0; r < 4; ++r) {
                float v = fmaxf(fmaxf(s[m2][0][r], s[m2][1][r]), fmaxf(s[m2][2][r], s[m2][3][r]));
                v = fmaxf(v, __shfl_xor(v, 1));
                v = fmaxf(v, __shfl_xor(v, 2));
                v = fmaxf(v, __shfl_xor(v, 4));
                v = fmaxf(v, __shfl_xor(v, 8));
                rmax[m2][r] = v;
                need |= (v > mx[m2][r] + 8.f) ? 1 : 0;
            }
        if (__any(need)) {
            #pragma unroll
            for (int m2 = 0; m2 < 2; ++m2)
                #pragma unroll
                for (int r = 0; r < 4; ++r) {
                    float mn = fmaxf(mx[m2][r], rmax[m2][r]);
                    float a  = __expf(mx[m2][r] - mn);
                    mx[m2][r] = mn;
                    l[m2][r] *= a;
                    #pragma unroll
                    for (int cc = 0; cc < 8; ++cc) O[m2][cc][r] *= a;
                }
        }
        #pragma unroll
        for (int m2 = 0; m2 < 2; ++m2)
            #pragma unroll
            for (int r = 0; r < 4; ++r) {
                float p0 = __expf(s[m2][0][r] - mx[m2][r]);
                float p1 = __expf(s[m2][1][r] - mx[m2][r]);
                float p2 = __expf(s[m2][2][r] - mx[m2][r]);
                float p3 = __expf(s[m2][3][r] - mx[m2][r]);
                float rs = (p0 + p1) + (p2 + p3);
                rs += __shfl_xor(rs, 1);
                rs += __shfl_xor(rs, 2);
                rs += __shfl_xor(rs, 4);
                rs += __shfl_xor(rs, 8);
                l[m2][r] += rs;
                short* pr = &P_lds[wave][(m2 * 16 + lg * 4 + r) * 72];
                pr[lr]      = f2bf(p0);
                pr[16 + lr] = f2bf(p1);
                pr[32 + lr] = f2bf(p2);
                pr[48 + lr] = f2bf(p3);
            }

        // ---- O += P V : 4 + 16 ds_reads, 32 MFMA
        bf16x8 pa[2][2];
        #pragma unroll
        for (int m2 = 0; m2 < 2; ++m2)
            #pragma unroll
            for (int kt = 0; kt < 2; ++kt)
                pa[m2][kt] = ldf(&P_lds[wave][(m2 * 16 + lr) * 72 + kt * 32 + lg * 8]);
        const int csw = (lr & 7) << 4;
        #pragma unroll
        for (int cc = 0; cc < 8; ++cc) {
            #pragma unroll
            for (int kt = 0; kt < 2; ++kt) {
                bf16x8 vf = *(const bf16x8*)(V_lds + (cc * 16 + lr) * 128 + ((kt * 64 + lg * 16) ^ csw));
                O[0][cc] = mfma16(pa[0][kt], vf, O[0][cc]);
                O[1][cc] = mfma16(pa[1][kt], vf, O[1][cc]);
            }
        }
    }

    // ---- epilogue: normalized bf16 partial + lse
    const size_t obase = (size_t)(ks * NB + n) * HW;
    #pragma unroll
    for (int m2 = 0; m2 < 2; ++m2) {
        float inv[4];
        #pragma unroll
        for (int r = 0; r < 4; ++r) inv[r] = 1.f / l[m2][r];
        #pragma unroll
        for (int cc = 0; cc < 8; ++cc)
            #pragma unroll
            for (int r = 0; r < 4; ++r) {
                int q = q0 + m2 * 16 + lg * 4 + r;
                Op[(obase + q) * ICH + cc * 16 + lr] = f2bf(O[m2][cc][r] * inv[r]);
            }
        if (lr == 0) {
            #pragma unroll
            for (int r = 0; r < 4; ++r) {
                int q = q0 + m2 * 16 + lg * 4 + r;
                Ls[obase + q] = mx[m2][r] + __logf(l[m2][r]);
            }
        }
    }
}

// ---------------------------------------------------------------------------
// K3b: combine the 8 k-split partials. grid 8192 x 256 (2 rows/block).
// ---------------------------------------------------------------------------
__global__ __launch_bounds__(256) void k_comb(const short* __restrict__ Op,
                                              const float* __restrict__ Ls,
                                              short* __restrict__ Obf) {
    const int ridx = blockIdx.x * 2 + (threadIdx.x >> 7);
    const int c    = threadIdx.x & 127;
    float lse[KSPL];
    float M = -INFINITY;
    #pragma unroll
    for (int i = 0; i < KSPL; ++i) {
        lse[i] = Ls[(size_t)i * (NB * HW) + ridx];
        M = fmaxf(M, lse[i]);
    }
    float ws = 0.f, acc = 0.f;
    #pragma unroll
    for (int i = 0; i < KSPL; ++i) {
        float w = __expf(lse[i] - M);
        ws += w;
        acc += w * bf2f(Op[((size_t)i * (NB * HW) + ridx) * ICH + c]);
    }
    Obf[(size_t)ridx * ICH + c] = f2bf(acc / ws);
}

// ---------------------------------------------------------------------------
// K4: out[n,o,q] = sum_c ww[o,c]*O[q,c] + feature[n,o,5,q]
// ---------------------------------------------------------------------------
__global__ __launch_bounds__(256) void k_out(const short* __restrict__ Obf,
                                             const short* __restrict__ wwb,
                                             const float* __restrict__ feat,
                                             float* __restrict__ out) {
    const int n    = blockIdx.y;
    const int wave = threadIdx.x >> 6;
    const int lane = threadIdx.x & 63;
    const int lr = lane & 15, lg = lane >> 4;
    const int q0 = blockIdx.x * 64;
    const int o0 = wave * 64;
    const short* On = Obf + (size_t)n * HW * ICH;

    f32x4 acc[4][4];
    #pragma unroll
    for (int i = 0; i < 4; ++i)
        #pragma unroll
        for (int jn = 0; jn < 4; ++jn) { acc[i][jn][0]=0.f; acc[i][jn][1]=0.f; acc[i][jn][2]=0.f; acc[i][jn][3]=0.f; }

    #pragma unroll
    for (int cf = 0; cf < 4; ++cf) {
        bf16x8 bO[4];
        #pragma unroll
        for (int nf = 0; nf < 4; ++nf)
            bO[nf] = ldf(On + (q0 + nf * 16 + lr) * ICH + cf * 32 + lg * 8);
        #pragma unroll
        for (int mf = 0; mf < 4; ++mf) {
            bf16x8 a = ldf(wwb + (o0 + mf * 16 + lr) * ICH + cf * 32 + lg * 8);
            #pragma unroll
            for (int nf = 0; nf < 4; ++nf)
                acc[mf][nf] = mfma16(a, bO[nf], acc[mf][nf]);
        }
    }
    #pragma unroll
    for (int mf = 0; mf < 4; ++mf) {
        #pragma unroll
        for (int nf = 0; nf < 4; ++nf) {
            #pragma unroll
            for (int r = 0; r < 4; ++r) {
                int o = o0 + mf * 16 + lg * 4 + r;
                int q = q0 + nf * 16 + lr;
                long long cxi = (((long long)(n * CIN + o)) * 9 + 5) * HW + q;
                out[((long long)(n * CIN + o)) * HW + q] = acc[mf][nf][r] + feat[cxi];
            }
        }
    }
}

// ---------------------------------------------------------------------------
extern "C" void kernel_launch(void* const* d_in, const int* in_sizes, int n_in,
                              void* d_out, int out_size, void* d_ws, size_t ws_size,
                              hipStream_t stream) {
    const float* feat = (const float*)d_in[0];
    const float* wth  = (const float*)d_in[1];
    const float* gth  = (const float*)d_in[2];
    const float* bth  = (const float*)d_in[3];
    const float* mth  = (const float*)d_in[4];
    const float* vth  = (const float*)d_in[5];
    const float* wph  = (const float*)d_in[6];
    const float* gph  = (const float*)d_in[7];
    const float* bph  = (const float*)d_in[8];
    const float* mph  = (const float*)d_in[9];
    const float* vph  = (const float*)d_in[10];
    const float* wg   = (const float*)d_in[11];
    const float* ww   = (const float*)d_in[12];
    float* out = (float*)d_out;

    size_t off = 0;
    auto carve = [&](size_t bytes) {
        void* p = (char*)d_ws + off;
        off += (bytes + 255) & ~(size_t)255;
        return p;
    };
    short* Xbf   = (short*)carve((size_t)NB * HW * CIN * 2);
    short* CXbf  = (short*)carve((size_t)NB * HW * CIN * 2);
    short* theta = (short*)carve((size_t)NB * HW * ICH * 2);
    short* phi   = (short*)carve((size_t)NB * HW * ICH * 2);
    short* Vt    = (short*)carve((size_t)NB * ICH * HW * 2);
    short* Obf   = (short*)carve((size_t)NB * HW * ICH * 2);
    short* Op    = (short*)carve((size_t)KSPL * NB * HW * ICH * 2);
    float* Ls    = (float*)carve((size_t)KSPL * NB * HW * 4);
    short* wthb  = (short*)carve((size_t)ICH * CIN * 2);
    short* wphb  = (short*)carve((size_t)ICH * CIN * 2);
    short* wgb   = (short*)carve((size_t)ICH * CIN * 2);
    short* wwb   = (short*)carve((size_t)CIN * ICH * 2);
    float* bnp   = (float*)carve((size_t)4 * ICH * 4);

    k_prep_w<<<128, 256, 0, stream>>>(wth, wph, wg, ww, gth, bth, mth, vth,
                                      gph, bph, mph, vph, wthb, wphb, wgb, wwb, bnp);
    k_prep_x<<<dim3(64, 8, NB), 256, 0, stream>>>(feat, Xbf, CXbf);
    k_conv3<<<dim3(64, NB), 256, 0, stream>>>(Xbf, CXbf, wthb, wphb, wgb, bnp,
                                              theta, phi, Vt);
    k_attn<<<1024, 256, 0, stream>>>(theta, phi, Vt, Op, Ls);
    k_comb<<<8192, 256, 0, stream>>>(Op, Ls, Obf);
    k_out<<<dim3(64, NB), 256, 0, stream>>>(Obf, wwb, feat, out);
}

// Round 3
// 182.891 us; speedup vs baseline: 2.0975x; 1.1388x over previous
//
#include <hip/hip_runtime.h>
#include <math.h>

#define HW   4096
#define CIN  256
#define ICH  128
#define NB   4
#define KSPL 8
#define KVB  32
#define TILES 16   // 512 keys per split / 32

typedef __attribute__((ext_vector_type(4))) float f32x4;
typedef __attribute__((ext_vector_type(8))) short bf16x8;

typedef const __attribute__((address_space(1))) void* gptr_t;
typedef __attribute__((address_space(3))) void* lptr_t;

__device__ inline short f2bf(float f) {
    unsigned int u = __float_as_uint(f);
    u += 0x7fffU + ((u >> 16) & 1U);   // round-to-nearest-even
    return (short)(u >> 16);
}

__device__ inline float bf2f(short s) {
    return __uint_as_float(((unsigned int)(unsigned short)s) << 16);
}

__device__ inline float exp2a(float x) {  // 2^x, handles -inf -> 0
    float r;
    asm("v_exp_f32 %0, %1" : "=v"(r) : "v"(x));
    return r;
}
__device__ inline float log2a(float x) {
    float r;
    asm("v_log_f32 %0, %1" : "=v"(r) : "v"(x));
    return r;
}

__device__ inline f32x4 mfma16(bf16x8 a, bf16x8 b, f32x4 c) {
    return __builtin_amdgcn_mfma_f32_16x16x32_bf16(a, b, c, 0, 0, 0);
}

__device__ inline bf16x8 ldf(const short* p) { return *(const bf16x8*)p; }

// ---------------------------------------------------------------------------
// K0: weights -> bf16; fold BN params. Theta's BN scale/bias additionally
// folded with log2(e) so attention logits are already base-2.
// ---------------------------------------------------------------------------
__global__ void k_prep_w(const float* __restrict__ wth, const float* __restrict__ wph,
                         const float* __restrict__ wg,  const float* __restrict__ ww,
                         const float* __restrict__ gth, const float* __restrict__ bth,
                         const float* __restrict__ mth, const float* __restrict__ vth,
                         const float* __restrict__ gph, const float* __restrict__ bph,
                         const float* __restrict__ mph, const float* __restrict__ vph,
                         short* __restrict__ wthb, short* __restrict__ wphb,
                         short* __restrict__ wgb,  short* __restrict__ wwb,
                         float* __restrict__ bnp) {
    const float LOG2E = 1.44269504f;
    int i = blockIdx.x * 256 + threadIdx.x;
    wthb[i] = f2bf(wth[i]);
    wphb[i] = f2bf(wph[i]);
    wgb[i]  = f2bf(wg[i]);
    wwb[i]  = f2bf(ww[i]);
    if (blockIdx.x == 0 && threadIdx.x < ICH) {
        int o = threadIdx.x;
        float s1 = gth[o] * rsqrtf(vth[o] + 1e-5f);
        bnp[o]        = s1 * LOG2E;
        bnp[ICH + o]  = (bth[o] - mth[o] * s1) * LOG2E;
        float s2 = gph[o] * rsqrtf(vph[o] + 1e-5f);
        bnp[2*ICH + o] = s2;
        bnp[3*ICH + o] = bph[o] - mph[o] * s2;
    }
}

// ---------------------------------------------------------------------------
// K1: x = max_d(feature), cx = feature[:, :, 5]; write (n,q,c) bf16.
// float4 loads (16B/lane), ushort4 writes (8B/lane).
// ---------------------------------------------------------------------------
__global__ __launch_bounds__(256) void k_prep_x(const float* __restrict__ feat,
                                                short* __restrict__ Xbf,
                                                short* __restrict__ CXbf) {
    const int q0 = blockIdx.x * 64;
    const int c0 = blockIdx.y * 32;
    const int n  = blockIdx.z;
    __shared__ float xs[32][68];
    __shared__ float cxs[32][68];
    const int tid = threadIdx.x;
    const int qv  = (tid & 15) * 4;
    const int ci  = tid >> 4;          // 0..15

    #pragma unroll
    for (int h = 0; h < 2; ++h) {
        const int cc = h * 16 + ci;
        const float* fp = feat + ((size_t)(n * CIN + c0 + cc)) * 9 * HW + q0 + qv;
        float4 mx = *(const float4*)fp;
        float4 cx = make_float4(0.f, 0.f, 0.f, 0.f);
        #pragma unroll
        for (int d = 1; d < 9; ++d) {
            float4 v = *(const float4*)(fp + (size_t)d * HW);
            if (d == 5) cx = v;
            mx.x = fmaxf(mx.x, v.x); mx.y = fmaxf(mx.y, v.y);
            mx.z = fmaxf(mx.z, v.z); mx.w = fmaxf(mx.w, v.w);
        }
        *(float4*)&xs[cc][qv]  = mx;
        *(float4*)&cxs[cc][qv] = cx;
    }
    __syncthreads();
    #pragma unroll
    for (int it = 0; it < 2; ++it) {
        const int q  = it * 32 + (tid >> 3);
        const int cq = (tid & 7) * 4;
        ushort4 ox, oc;
        ox.x = (unsigned short)f2bf(xs[cq][q]);
        ox.y = (unsigned short)f2bf(xs[cq + 1][q]);
        ox.z = (unsigned short)f2bf(xs[cq + 2][q]);
        ox.w = (unsigned short)f2bf(xs[cq + 3][q]);
        oc.x = (unsigned short)f2bf(cxs[cq][q]);
        oc.y = (unsigned short)f2bf(cxs[cq + 1][q]);
        oc.z = (unsigned short)f2bf(cxs[cq + 2][q]);
        oc.w = (unsigned short)f2bf(cxs[cq + 3][q]);
        const size_t ob = ((size_t)n * HW + q0 + q) * CIN + c0 + cq;
        *(ushort4*)&Xbf[ob]  = ox;
        *(ushort4*)&CXbf[ob] = oc;
    }
}

// ---------------------------------------------------------------------------
// K2: theta/phi (q,c) with BN+ReLU (theta pre-scaled by log2e via bnp);
//     g with swapped roles -> Vt (c,k).
// ---------------------------------------------------------------------------
__global__ __launch_bounds__(256) void k_conv3(const short* __restrict__ Xbf,
                                               const short* __restrict__ CXbf,
                                               const short* __restrict__ wthb,
                                               const short* __restrict__ wphb,
                                               const short* __restrict__ wgb,
                                               const float* __restrict__ bnp,
                                               short* __restrict__ theta,
                                               short* __restrict__ phi,
                                               short* __restrict__ Vt) {
    const int n    = blockIdx.y;
    const int wave = threadIdx.x >> 6;
    const int lane = threadIdx.x & 63;
    const int lr = lane & 15, lg = lane >> 4;
    const int q0 = blockIdx.x * 64 + wave * 16;
    const short* Xn  = Xbf  + (size_t)n * HW * CIN;
    const short* CXn = CXbf + (size_t)n * HW * CIN;
    short* thn = theta + (size_t)n * HW * ICH;
    short* phn = phi   + (size_t)n * HW * ICH;
    short* vtn = Vt    + (size_t)n * ICH * HW;

    f32x4 acc[8];
    #pragma unroll
    for (int i = 0; i < 8; ++i) { acc[i][0]=0.f; acc[i][1]=0.f; acc[i][2]=0.f; acc[i][3]=0.f; }
    #pragma unroll
    for (int cf = 0; cf < 8; ++cf) {
        bf16x8 a = ldf(CXn + (q0 + lr) * CIN + cf * 32 + lg * 8);
        #pragma unroll
        for (int of = 0; of < 8; ++of) {
            bf16x8 b = ldf(wthb + (of * 16 + lr) * CIN + cf * 32 + lg * 8);
            acc[of] = mfma16(a, b, acc[of]);
        }
    }
    #pragma unroll
    for (int of = 0; of < 8; ++of) {
        int o = of * 16 + lr;
        float sA = bnp[o], sB = bnp[ICH + o];
        #pragma unroll
        for (int r = 0; r < 4; ++r) {
            int q = q0 + lg * 4 + r;
            thn[q * ICH + o] = f2bf(fmaxf(acc[of][r] * sA + sB, 0.f));
        }
    }

    #pragma unroll
    for (int i = 0; i < 8; ++i) { acc[i][0]=0.f; acc[i][1]=0.f; acc[i][2]=0.f; acc[i][3]=0.f; }
    #pragma unroll
    for (int cf = 0; cf < 8; ++cf) {
        bf16x8 a = ldf(Xn + (q0 + lr) * CIN + cf * 32 + lg * 8);
        #pragma unroll
        for (int of = 0; of < 8; ++of) {
            bf16x8 b = ldf(wphb + (of * 16 + lr) * CIN + cf * 32 + lg * 8);
            acc[of] = mfma16(a, b, acc[of]);
        }
    }
    #pragma unroll
    for (int of = 0; of < 8; ++of) {
        int o = of * 16 + lr;
        float sA = bnp[2*ICH + o], sB = bnp[3*ICH + o];
        #pragma unroll
        for (int r = 0; r < 4; ++r) {
            int q = q0 + lg * 4 + r;
            phn[q * ICH + o] = f2bf(fmaxf(acc[of][r] * sA + sB, 0.f));
        }
    }

    #pragma unroll
    for (int i = 0; i < 8; ++i) { acc[i][0]=0.f; acc[i][1]=0.f; acc[i][2]=0.f; acc[i][3]=0.f; }
    #pragma unroll
    for (int cf = 0; cf < 8; ++cf) {
        bf16x8 bx = ldf(Xn + (q0 + lr) * CIN + cf * 32 + lg * 8);
        #pragma unroll
        for (int mf = 0; mf < 8; ++mf) {
            bf16x8 a = ldf(wgb + (mf * 16 + lr) * CIN + cf * 32 + lg * 8);
            acc[mf] = mfma16(a, bx, acc[mf]);
        }
    }
    #pragma unroll
    for (int mf = 0; mf < 8; ++mf) {
        #pragma unroll
        for (int r = 0; r < 4; ++r) {
            int o = mf * 16 + lg * 4 + r;
            vtn[(size_t)o * HW + q0 + lr] = f2bf(acc[mf][r]);
        }
    }
}

// ---------------------------------------------------------------------------
// K3: flash attention, k-split x8, base-2 softmax, defer-max (THR=11),
// deferred l-reduce, 2-phase double-buffered K (global_load_lds, swizzled
// source) + V (reg-staged into 80B-stride LDS). One barrier per 32-key tile.
// grid 1024 x 256 (4 waves x 32 q-rows). XCD mapping: n = (bid&7)>>1.
// ---------------------------------------------------------------------------
__global__ __launch_bounds__(256, 3) void k_attn(const short* __restrict__ theta,
                                                 const short* __restrict__ phi,
                                                 const short* __restrict__ Vt,
                                                 short* __restrict__ Op,
                                                 float* __restrict__ Ls) {
    __shared__ char  K_lds[2][8192];        // 32 keys x 128 ch bf16, XOR-swizzled
    __shared__ short V_lds[2][128 * 40];    // 128 ch x 32 keys, stride 40 shorts
    __shared__ short P_lds[4][32 * 40];     // per-wave P, stride 40 shorts

    const int bid  = blockIdx.x;
    const int j    = bid & 7;
    const int n    = j >> 1;
    const int rest = ((bid >> 3) << 1) | (j & 1);   // 0..255
    const int qb   = rest >> 3;                     // 0..31
    const int ks   = rest & 7;                      // 0..7
    const int tid  = threadIdx.x;
    const int wave = tid >> 6;
    const int lane = tid & 63;
    const int lr = lane & 15, lg = lane >> 4;
    const int q0 = qb * 128 + wave * 32;
    const int kbase = ks * 512;

    const short* Qn = theta + (size_t)n * HW * ICH;
    const short* Kn = phi   + (size_t)n * HW * ICH;
    const short* Vn = Vt    + (size_t)n * ICH * HW;

    bf16x8 aq[2][4];
    #pragma unroll
    for (int m2 = 0; m2 < 2; ++m2)
        #pragma unroll
        for (int cf = 0; cf < 4; ++cf)
            aq[m2][cf] = ldf(Qn + (q0 + m2 * 16 + lr) * ICH + cf * 32 + lg * 8);

    f32x4 O[2][8];
    #pragma unroll
    for (int m2 = 0; m2 < 2; ++m2)
        #pragma unroll
        for (int i = 0; i < 8; ++i) { O[m2][i][0]=0.f; O[m2][i][1]=0.f; O[m2][i][2]=0.f; O[m2][i][3]=0.f; }
    float mx[2][4], l[2][4];
    #pragma unroll
    for (int m2 = 0; m2 < 2; ++m2)
        #pragma unroll
        for (int r = 0; r < 4; ++r) { mx[m2][r] = -INFINITY; l[m2][r] = 0.f; }

    bf16x8 vr0, vr1;
    auto stageK = [&](int tt, int pp) {
        #pragma unroll
        for (int i = 0; i < 2; ++i) {
            const int o   = wave * 2048 + i * 1024 + lane * 16;  // linear dest byte
            const int row = o >> 8;
            const int cb  = (o & 255) ^ ((row & 7) << 4);
            const char* src = (const char*)Kn + (size_t)(kbase + tt * KVB + row) * 256 + cb;
            __builtin_amdgcn_global_load_lds((gptr_t)src,
                (lptr_t)(&K_lds[pp][wave * 2048 + i * 1024]), 16, 0, 0);
        }
    };
    auto loadV = [&](int tt) {
        vr0 = ldf(Vn + (size_t)(tid >> 2) * HW + kbase + tt * KVB + (tid & 3) * 8);
        vr1 = ldf(Vn + (size_t)((tid + 256) >> 2) * HW + kbase + tt * KVB + (tid & 3) * 8);
    };
    auto writeV = [&](int pp) {
        *(bf16x8*)&V_lds[pp][(tid >> 2) * 40 + (tid & 3) * 8] = vr0;
        *(bf16x8*)&V_lds[pp][((tid + 256) >> 2) * 40 + (tid & 3) * 8] = vr1;
    };

    // prologue: stage tile 0 into buffer 0
    stageK(0, 0);
    loadV(0);
    writeV(0);
    __syncthreads();

    for (int t = 0; t < TILES; ++t) {
        const int p = t & 1;
        const bool pre = (t + 1 < TILES);
        if (pre) { stageK(t + 1, p ^ 1); loadV(t + 1); }

        // ---- S = Q K^T (32q x 32k): 8 ds_read_b128 + 16 MFMA
        f32x4 s[2][2];
        #pragma unroll
        for (int m2 = 0; m2 < 2; ++m2)
            #pragma unroll
            for (int tt = 0; tt < 2; ++tt) { s[m2][tt][0]=0.f; s[m2][tt][1]=0.f; s[m2][tt][2]=0.f; s[m2][tt][3]=0.f; }
        __builtin_amdgcn_s_setprio(1);
        #pragma unroll
        for (int tt = 0; tt < 2; ++tt) {
            const int row = tt * 16 + lr;
            const int rsw = (row & 7) << 4;
            #pragma unroll
            for (int cf = 0; cf < 4; ++cf) {
                bf16x8 kf = *(const bf16x8*)(&K_lds[p][row * 256 + ((cf * 64 + lg * 16) ^ rsw)]);
                s[0][tt] = mfma16(aq[0][cf], kf, s[0][tt]);
                s[1][tt] = mfma16(aq[1][cf], kf, s[1][tt]);
            }
        }
        __builtin_amdgcn_s_setprio(0);

        // ---- softmax (base-2, defer-max THR=11, per-lane partial l)
        float lm[2][4];
        int need = 0;
        #pragma unroll
        for (int m2 = 0; m2 < 2; ++m2)
            #pragma unroll
            for (int r = 0; r < 4; ++r) {
                lm[m2][r] = fmaxf(s[m2][0][r], s[m2][1][r]);
                need |= (lm[m2][r] > mx[m2][r] + 11.f) ? 1 : 0;
            }
        if (__any(need)) {
            #pragma unroll
            for (int m2 = 0; m2 < 2; ++m2)
                #pragma unroll
                for (int r = 0; r < 4; ++r) {
                    float v = lm[m2][r];
                    v = fmaxf(v, __shfl_xor(v, 1));
                    v = fmaxf(v, __shfl_xor(v, 2));
                    v = fmaxf(v, __shfl_xor(v, 4));
                    v = fmaxf(v, __shfl_xor(v, 8));
                    float mn = fmaxf(mx[m2][r], v);
                    float a  = exp2a(mx[m2][r] - mn);
                    mx[m2][r] = mn;
                    l[m2][r] *= a;
                    #pragma unroll
                    for (int cc = 0; cc < 8; ++cc) O[m2][cc][r] *= a;
                }
        }
        #pragma unroll
        for (int m2 = 0; m2 < 2; ++m2)
            #pragma unroll
            for (int r = 0; r < 4; ++r) {
                float p0 = exp2a(s[m2][0][r] - mx[m2][r]);
                float p1 = exp2a(s[m2][1][r] - mx[m2][r]);
                l[m2][r] += p0 + p1;
                short* pr = &P_lds[wave][(m2 * 16 + lg * 4 + r) * 40];
                pr[lr]      = f2bf(p0);
                pr[16 + lr] = f2bf(p1);
            }

        // ---- O += P V : 10 ds_read_b128 + 16 MFMA
        bf16x8 pa0 = ldf(&P_lds[wave][lr * 40 + lg * 8]);
        bf16x8 pa1 = ldf(&P_lds[wave][(16 + lr) * 40 + lg * 8]);
        __builtin_amdgcn_s_setprio(1);
        #pragma unroll
        for (int cc = 0; cc < 8; ++cc) {
            bf16x8 vf = *(const bf16x8*)(&V_lds[p][(cc * 16 + lr) * 40 + lg * 8]);
            O[0][cc] = mfma16(pa0, vf, O[0][cc]);
            O[1][cc] = mfma16(pa1, vf, O[1][cc]);
        }
        __builtin_amdgcn_s_setprio(0);

        if (pre) writeV(p ^ 1);
        __syncthreads();
    }

    // ---- epilogue: reduce l across the 16-lane group, write partial + lse2
    const size_t obase = (size_t)(ks * NB + n) * HW;
    #pragma unroll
    for (int m2 = 0; m2 < 2; ++m2) {
        float inv[4];
        #pragma unroll
        for (int r = 0; r < 4; ++r) {
            float v = l[m2][r];
            v += __shfl_xor(v, 1);
            v += __shfl_xor(v, 2);
            v += __shfl_xor(v, 4);
            v += __shfl_xor(v, 8);
            l[m2][r] = v;
            inv[r] = 1.f / v;
        }
        #pragma unroll
        for (int cc = 0; cc < 8; ++cc)
            #pragma unroll
            for (int r = 0; r < 4; ++r) {
                int q = q0 + m2 * 16 + lg * 4 + r;
                Op[(obase + q) * ICH + cc * 16 + lr] = f2bf(O[m2][cc][r] * inv[r]);
            }
        if (lr == 0) {
            #pragma unroll
            for (int r = 0; r < 4; ++r) {
                int q = q0 + m2 * 16 + lg * 4 + r;
                Ls[obase + q] = mx[m2][r] + log2a(l[m2][r]);
            }
        }
    }
}

// ---------------------------------------------------------------------------
// K4: fused combine + final conv + residual.
// out[n,o,q] = sum_c ww[o,c] * (sum_i w_i(q) Op_i[q,c]) + feature[n,o,5,q]
// grid (128, 4) x 256.
// ---------------------------------------------------------------------------
__global__ __launch_bounds__(256) void k_out(const short* __restrict__ Op,
                                             const float* __restrict__ Ls,
                                             const short* __restrict__ wwb,
                                             const float* __restrict__ feat,
                                             float* __restrict__ out) {
    const int n    = blockIdx.y;
    const int wave = threadIdx.x >> 6;
    const int lane = threadIdx.x & 63;
    const int lr = lane & 15, lg = lane >> 4;
    const int q0 = blockIdx.x * 32;
    const int o0 = wave * 64;

    // combine weights for this lane's q rows (base-2 lse)
    float w[2][KSPL];
    #pragma unroll
    for (int nf = 0; nf < 2; ++nf) {
        const int q = q0 + nf * 16 + lr;
        float ls[KSPL], M = -INFINITY;
        #pragma unroll
        for (int i = 0; i < KSPL; ++i) {
            ls[i] = Ls[((size_t)i * NB + n) * HW + q];
            M = fmaxf(M, ls[i]);
        }
        float ws = 0.f;
        #pragma unroll
        for (int i = 0; i < KSPL; ++i) { w[nf][i] = exp2a(ls[i] - M); ws += w[nf][i]; }
        float inv = 1.f / ws;
        #pragma unroll
        for (int i = 0; i < KSPL; ++i) w[nf][i] *= inv;
    }

    f32x4 acc[4][2];
    #pragma unroll
    for (int i = 0; i < 4; ++i)
        #pragma unroll
        for (int jn = 0; jn < 2; ++jn) { acc[i][jn][0]=0.f; acc[i][jn][1]=0.f; acc[i][jn][2]=0.f; acc[i][jn][3]=0.f; }

    #pragma unroll
    for (int cf = 0; cf < 4; ++cf) {
        bf16x8 bO[2];
        #pragma unroll
        for (int nf = 0; nf < 2; ++nf) {
            const size_t base = ((size_t)n * HW + q0 + nf * 16 + lr) * ICH + cf * 32 + lg * 8;
            float fo[8] = {0.f,0.f,0.f,0.f,0.f,0.f,0.f,0.f};
            #pragma unroll
            for (int i = 0; i < KSPL; ++i) {
                bf16x8 v = ldf(Op + (size_t)i * NB * HW * ICH + base);
                #pragma unroll
                for (int e = 0; e < 8; ++e) fo[e] += w[nf][i] * bf2f(v[e]);
            }
            #pragma unroll
            for (int e = 0; e < 8; ++e) bO[nf][e] = f2bf(fo[e]);
        }
        #pragma unroll
        for (int mf = 0; mf < 4; ++mf) {
            bf16x8 a = ldf(wwb + (o0 + mf * 16 + lr) * ICH + cf * 32 + lg * 8);
            #pragma unroll
            for (int nf = 0; nf < 2; ++nf)
                acc[mf][nf] = mfma16(a, bO[nf], acc[mf][nf]);
        }
    }
    #pragma unroll
    for (int mf = 0; mf < 4; ++mf) {
        #pragma unroll
        for (int nf = 0; nf < 2; ++nf) {
            #pragma unroll
            for (int r = 0; r < 4; ++r) {
                int o = o0 + mf * 16 + lg * 4 + r;
                int q = q0 + nf * 16 + lr;
                long long cxi = (((long long)(n * CIN + o)) * 9 + 5) * HW + q;
                out[((long long)(n * CIN + o)) * HW + q] = acc[mf][nf][r] + feat[cxi];
            }
        }
    }
}

// ---------------------------------------------------------------------------
extern "C" void kernel_launch(void* const* d_in, const int* in_sizes, int n_in,
                              void* d_out, int out_size, void* d_ws, size_t ws_size,
                              hipStream_t stream) {
    const float* feat = (const float*)d_in[0];
    const float* wth  = (const float*)d_in[1];
    const float* gth  = (const float*)d_in[2];
    const float* bth  = (const float*)d_in[3];
    const float* mth  = (const float*)d_in[4];
    const float* vth  = (const float*)d_in[5];
    const float* wph  = (const float*)d_in[6];
    const float* gph  = (const float*)d_in[7];
    const float* bph  = (const float*)d_in[8];
    const float* mph  = (const float*)d_in[9];
    const float* vph  = (const float*)d_in[10];
    const float* wg   = (const float*)d_in[11];
    const float* ww   = (const float*)d_in[12];
    float* out = (float*)d_out;

    size_t off = 0;
    auto carve = [&](size_t bytes) {
        void* p = (char*)d_ws + off;
        off += (bytes + 255) & ~(size_t)255;
        return p;
    };
    short* Xbf   = (short*)carve((size_t)NB * HW * CIN * 2);
    short* CXbf  = (short*)carve((size_t)NB * HW * CIN * 2);
    short* theta = (short*)carve((size_t)NB * HW * ICH * 2);
    short* phi   = (short*)carve((size_t)NB * HW * ICH * 2);
    short* Vt    = (short*)carve((size_t)NB * ICH * HW * 2);
    short* Op    = (short*)carve((size_t)KSPL * NB * HW * ICH * 2);
    float* Ls    = (float*)carve((size_t)KSPL * NB * HW * 4);
    short* wthb  = (short*)carve((size_t)ICH * CIN * 2);
    short* wphb  = (short*)carve((size_t)ICH * CIN * 2);
    short* wgb   = (short*)carve((size_t)ICH * CIN * 2);
    short* wwb   = (short*)carve((size_t)CIN * ICH * 2);
    float* bnp   = (float*)carve((size_t)4 * ICH * 4);

    k_prep_w<<<128, 256, 0, stream>>>(wth, wph, wg, ww, gth, bth, mth, vth,
                                      gph, bph, mph, vph, wthb, wphb, wgb, wwb, bnp);
    k_prep_x<<<dim3(64, 8, NB), 256, 0, stream>>>(feat, Xbf, CXbf);
    k_conv3<<<dim3(64, NB), 256, 0, stream>>>(Xbf, CXbf, wthb, wphb, wgb, bnp,
                                              theta, phi, Vt);
    k_attn<<<1024, 256, 0, stream>>>(theta, phi, Vt, Op, Ls);
    k_out<<<dim3(128, NB), 256, 0, stream>>>(Op, Ls, wwb, feat, out);
}

// Round 4
// 164.971 us; speedup vs baseline: 2.3254x; 1.1086x over previous
//
#include <hip/hip_runtime.h>
#include <math.h>

#define HW   4096
#define CIN  256
#define ICH  128
#define NB   4
#define KSPL 8
#define KVB  32
#define TILES 16   // 512 keys per split / 32

typedef __attribute__((ext_vector_type(4))) float f32x4;
typedef __attribute__((ext_vector_type(8))) short bf16x8;
typedef __attribute__((ext_vector_type(4))) short bf16x4;

typedef const __attribute__((address_space(1))) void* gptr_t;
typedef __attribute__((address_space(3))) void* lptr_t;

__device__ inline short f2bf(float f) {
    unsigned int u = __float_as_uint(f);
    u += 0x7fffU + ((u >> 16) & 1U);   // round-to-nearest-even
    return (short)(u >> 16);
}

__device__ inline float bf2f(short s) {
    return __uint_as_float(((unsigned int)(unsigned short)s) << 16);
}

__device__ inline float exp2a(float x) {  // 2^x, handles -inf -> 0
    float r;
    asm("v_exp_f32 %0, %1" : "=v"(r) : "v"(x));
    return r;
}
__device__ inline float log2a(float x) {
    float r;
    asm("v_log_f32 %0, %1" : "=v"(r) : "v"(x));
    return r;
}

__device__ inline f32x4 mfma16(bf16x8 a, bf16x8 b, f32x4 c) {
    return __builtin_amdgcn_mfma_f32_16x16x32_bf16(a, b, c, 0, 0, 0);
}

__device__ inline bf16x8 ldf(const short* p) { return *(const bf16x8*)p; }

// ---------------------------------------------------------------------------
// K0: weights -> bf16; fold BN params. Theta's BN scale/bias folded with
// log2(e) so attention logits are base-2.
// ---------------------------------------------------------------------------
__global__ void k_prep_w(const float* __restrict__ wth, const float* __restrict__ wph,
                         const float* __restrict__ wg,  const float* __restrict__ ww,
                         const float* __restrict__ gth, const float* __restrict__ bth,
                         const float* __restrict__ mth, const float* __restrict__ vth,
                         const float* __restrict__ gph, const float* __restrict__ bph,
                         const float* __restrict__ mph, const float* __restrict__ vph,
                         short* __restrict__ wthb, short* __restrict__ wphb,
                         short* __restrict__ wgb,  short* __restrict__ wwb,
                         float* __restrict__ bnp) {
    const float LOG2E = 1.44269504f;
    int i = blockIdx.x * 256 + threadIdx.x;
    wthb[i] = f2bf(wth[i]);
    wphb[i] = f2bf(wph[i]);
    wgb[i]  = f2bf(wg[i]);
    wwb[i]  = f2bf(ww[i]);
    if (blockIdx.x == 0 && threadIdx.x < ICH) {
        int o = threadIdx.x;
        float s1 = gth[o] * rsqrtf(vth[o] + 1e-5f);
        bnp[o]        = s1 * LOG2E;
        bnp[ICH + o]  = (bth[o] - mth[o] * s1) * LOG2E;
        float s2 = gph[o] * rsqrtf(vph[o] + 1e-5f);
        bnp[2*ICH + o] = s2;
        bnp[3*ICH + o] = bph[o] - mph[o] * s2;
    }
}

// ---------------------------------------------------------------------------
// K1: x = max_d(feature), cx = feature[:, :, 5]; write (n,q,c) bf16.
// ---------------------------------------------------------------------------
__global__ __launch_bounds__(256) void k_prep_x(const float* __restrict__ feat,
                                                short* __restrict__ Xbf,
                                                short* __restrict__ CXbf) {
    const int q0 = blockIdx.x * 64;
    const int c0 = blockIdx.y * 32;
    const int n  = blockIdx.z;
    __shared__ float xs[32][68];
    __shared__ float cxs[32][68];
    const int tid = threadIdx.x;
    const int qv  = (tid & 15) * 4;
    const int ci  = tid >> 4;          // 0..15

    #pragma unroll
    for (int h = 0; h < 2; ++h) {
        const int cc = h * 16 + ci;
        const float* fp = feat + ((size_t)(n * CIN + c0 + cc)) * 9 * HW + q0 + qv;
        float4 mx = *(const float4*)fp;
        float4 cx = make_float4(0.f, 0.f, 0.f, 0.f);
        #pragma unroll
        for (int d = 1; d < 9; ++d) {
            float4 v = *(const float4*)(fp + (size_t)d * HW);
            if (d == 5) cx = v;
            mx.x = fmaxf(mx.x, v.x); mx.y = fmaxf(mx.y, v.y);
            mx.z = fmaxf(mx.z, v.z); mx.w = fmaxf(mx.w, v.w);
        }
        *(float4*)&xs[cc][qv]  = mx;
        *(float4*)&cxs[cc][qv] = cx;
    }
    __syncthreads();
    #pragma unroll
    for (int it = 0; it < 2; ++it) {
        const int q  = it * 32 + (tid >> 3);
        const int cq = (tid & 7) * 4;
        ushort4 ox, oc;
        ox.x = (unsigned short)f2bf(xs[cq][q]);
        ox.y = (unsigned short)f2bf(xs[cq + 1][q]);
        ox.z = (unsigned short)f2bf(xs[cq + 2][q]);
        ox.w = (unsigned short)f2bf(xs[cq + 3][q]);
        oc.x = (unsigned short)f2bf(cxs[cq][q]);
        oc.y = (unsigned short)f2bf(cxs[cq + 1][q]);
        oc.z = (unsigned short)f2bf(cxs[cq + 2][q]);
        oc.w = (unsigned short)f2bf(cxs[cq + 3][q]);
        const size_t ob = ((size_t)n * HW + q0 + q) * CIN + c0 + cq;
        *(ushort4*)&Xbf[ob]  = ox;
        *(ushort4*)&CXbf[ob] = oc;
    }
}

// ---------------------------------------------------------------------------
// K2: theta/phi (q,c) with BN+ReLU (theta pre-scaled by log2e via bnp);
//     g with swapped roles -> Vt (c,k).
// ---------------------------------------------------------------------------
__global__ __launch_bounds__(256) void k_conv3(const short* __restrict__ Xbf,
                                               const short* __restrict__ CXbf,
                                               const short* __restrict__ wthb,
                                               const short* __restrict__ wphb,
                                               const short* __restrict__ wgb,
                                               const float* __restrict__ bnp,
                                               short* __restrict__ theta,
                                               short* __restrict__ phi,
                                               short* __restrict__ Vt) {
    const int n    = blockIdx.y;
    const int wave = threadIdx.x >> 6;
    const int lane = threadIdx.x & 63;
    const int lr = lane & 15, lg = lane >> 4;
    const int q0 = blockIdx.x * 64 + wave * 16;
    const short* Xn  = Xbf  + (size_t)n * HW * CIN;
    const short* CXn = CXbf + (size_t)n * HW * CIN;
    short* thn = theta + (size_t)n * HW * ICH;
    short* phn = phi   + (size_t)n * HW * ICH;
    short* vtn = Vt    + (size_t)n * ICH * HW;

    f32x4 acc[8];
    #pragma unroll
    for (int i = 0; i < 8; ++i) { acc[i][0]=0.f; acc[i][1]=0.f; acc[i][2]=0.f; acc[i][3]=0.f; }
    #pragma unroll
    for (int cf = 0; cf < 8; ++cf) {
        bf16x8 a = ldf(CXn + (q0 + lr) * CIN + cf * 32 + lg * 8);
        #pragma unroll
        for (int of = 0; of < 8; ++of) {
            bf16x8 b = ldf(wthb + (of * 16 + lr) * CIN + cf * 32 + lg * 8);
            acc[of] = mfma16(a, b, acc[of]);
        }
    }
    #pragma unroll
    for (int of = 0; of < 8; ++of) {
        int o = of * 16 + lr;
        float sA = bnp[o], sB = bnp[ICH + o];
        #pragma unroll
        for (int r = 0; r < 4; ++r) {
            int q = q0 + lg * 4 + r;
            thn[q * ICH + o] = f2bf(fmaxf(acc[of][r] * sA + sB, 0.f));
        }
    }

    #pragma unroll
    for (int i = 0; i < 8; ++i) { acc[i][0]=0.f; acc[i][1]=0.f; acc[i][2]=0.f; acc[i][3]=0.f; }
    #pragma unroll
    for (int cf = 0; cf < 8; ++cf) {
        bf16x8 a = ldf(Xn + (q0 + lr) * CIN + cf * 32 + lg * 8);
        #pragma unroll
        for (int of = 0; of < 8; ++of) {
            bf16x8 b = ldf(wphb + (of * 16 + lr) * CIN + cf * 32 + lg * 8);
            acc[of] = mfma16(a, b, acc[of]);
        }
    }
    #pragma unroll
    for (int of = 0; of < 8; ++of) {
        int o = of * 16 + lr;
        float sA = bnp[2*ICH + o], sB = bnp[3*ICH + o];
        #pragma unroll
        for (int r = 0; r < 4; ++r) {
            int q = q0 + lg * 4 + r;
            phn[q * ICH + o] = f2bf(fmaxf(acc[of][r] * sA + sB, 0.f));
        }
    }

    #pragma unroll
    for (int i = 0; i < 8; ++i) { acc[i][0]=0.f; acc[i][1]=0.f; acc[i][2]=0.f; acc[i][3]=0.f; }
    #pragma unroll
    for (int cf = 0; cf < 8; ++cf) {
        bf16x8 bx = ldf(Xn + (q0 + lr) * CIN + cf * 32 + lg * 8);
        #pragma unroll
        for (int mf = 0; mf < 8; ++mf) {
            bf16x8 a = ldf(wgb + (mf * 16 + lr) * CIN + cf * 32 + lg * 8);
            acc[mf] = mfma16(a, bx, acc[mf]);
        }
    }
    #pragma unroll
    for (int mf = 0; mf < 8; ++mf) {
        #pragma unroll
        for (int r = 0; r < 4; ++r) {
            int o = mf * 16 + lg * 4 + r;
            vtn[(size_t)o * HW + q0 + lr] = f2bf(acc[mf][r]);
        }
    }
}

// ---------------------------------------------------------------------------
// K3: flash attention, k-split x8, swapped-operand QK^T (S^T = mfma(K,Q)) so
// softmax + P are fully lane-local: lane holds P[keys lg*4+r, 16+lg*4+r][q=lr].
// PV uses the same k-permutation on the V A-fragments (sum-invariance), so P
// never leaves registers. Steady state: zero cross-lane ops (defer-max THR=11,
// per-lane partial l reduced in epilogue). K double-buffered via
// global_load_lds (swizzled source); V reg-staged into 80B-stride LDS.
// grid 1024 x 256 (4 waves x 32 q). XCD mapping: n = (bid&7)>>1.
// ---------------------------------------------------------------------------
__global__ __launch_bounds__(256, 3) void k_attn(const short* __restrict__ theta,
                                                 const short* __restrict__ phi,
                                                 const short* __restrict__ Vt,
                                                 short* __restrict__ Op,
                                                 float* __restrict__ Ls) {
    __shared__ char  K_lds[2][8192];        // 32 keys x 128 ch bf16, XOR-swizzled
    __shared__ short V_lds[2][128 * 40];    // 128 ch x 32 keys, stride 40 shorts

    const int bid  = blockIdx.x;
    const int j    = bid & 7;
    const int n    = j >> 1;
    const int rest = ((bid >> 3) << 1) | (j & 1);   // 0..255
    const int qb   = rest >> 3;                     // 0..31
    const int ks   = rest & 7;                      // 0..7
    const int tid  = threadIdx.x;
    const int wave = tid >> 6;
    const int lane = tid & 63;
    const int lr = lane & 15, lg = lane >> 4;
    const int q0 = qb * 128 + wave * 32;
    const int kbase = ks * 512;

    const short* Qn = theta + (size_t)n * HW * ICH;
    const short* Kn = phi   + (size_t)n * HW * ICH;
    const short* Vn = Vt    + (size_t)n * ICH * HW;

    bf16x8 aq[2][4];
    #pragma unroll
    for (int m2 = 0; m2 < 2; ++m2)
        #pragma unroll
        for (int cf = 0; cf < 4; ++cf)
            aq[m2][cf] = ldf(Qn + (q0 + m2 * 16 + lr) * ICH + cf * 32 + lg * 8);

    // O^T accumulators: O[m2][cc] rows c = cc*16+lg*4+r, col q = q0+m2*16+lr
    f32x4 O[2][8];
    #pragma unroll
    for (int m2 = 0; m2 < 2; ++m2)
        #pragma unroll
        for (int i = 0; i < 8; ++i) { O[m2][i][0]=0.f; O[m2][i][1]=0.f; O[m2][i][2]=0.f; O[m2][i][3]=0.f; }
    float mx[2] = { -INFINITY, -INFINITY };
    float l[2]  = { 0.f, 0.f };

    bf16x8 vr0, vr1;
    auto stageK = [&](int tt, int pp) {
        #pragma unroll
        for (int i = 0; i < 2; ++i) {
            const int o   = wave * 2048 + i * 1024 + lane * 16;  // linear dest byte
            const int row = o >> 8;
            const int cb  = (o & 255) ^ ((row & 7) << 4);
            const char* src = (const char*)Kn + (size_t)(kbase + tt * KVB + row) * 256 + cb;
            __builtin_amdgcn_global_load_lds((gptr_t)src,
                (lptr_t)(&K_lds[pp][wave * 2048 + i * 1024]), 16, 0, 0);
        }
    };
    auto loadV = [&](int tt) {
        vr0 = ldf(Vn + (size_t)(tid >> 2) * HW + kbase + tt * KVB + (tid & 3) * 8);
        vr1 = ldf(Vn + (size_t)((tid + 256) >> 2) * HW + kbase + tt * KVB + (tid & 3) * 8);
    };
    auto writeV = [&](int pp) {
        *(bf16x8*)&V_lds[pp][(tid >> 2) * 40 + (tid & 3) * 8] = vr0;
        *(bf16x8*)&V_lds[pp][((tid + 256) >> 2) * 40 + (tid & 3) * 8] = vr1;
    };

    stageK(0, 0);
    loadV(0);
    writeV(0);
    __syncthreads();

    for (int t = 0; t < TILES; ++t) {
        const int p = t & 1;
        const bool pre = (t + 1 < TILES);
        if (pre) { stageK(t + 1, p ^ 1); loadV(t + 1); }

        // ---- S^T = K Q^T : rows = keys, cols = q. s[tt][m2]
        f32x4 s[2][2];
        #pragma unroll
        for (int tt = 0; tt < 2; ++tt)
            #pragma unroll
            for (int m2 = 0; m2 < 2; ++m2) { s[tt][m2][0]=0.f; s[tt][m2][1]=0.f; s[tt][m2][2]=0.f; s[tt][m2][3]=0.f; }
        __builtin_amdgcn_s_setprio(1);
        #pragma unroll
        for (int tt = 0; tt < 2; ++tt) {
            const int row = tt * 16 + lr;
            const int rsw = (row & 7) << 4;
            #pragma unroll
            for (int cf = 0; cf < 4; ++cf) {
                bf16x8 kf = *(const bf16x8*)(&K_lds[p][row * 256 + ((cf * 64 + lg * 16) ^ rsw)]);
                s[tt][0] = mfma16(kf, aq[0][cf], s[tt][0]);
                s[tt][1] = mfma16(kf, aq[1][cf], s[tt][1]);
            }
        }
        __builtin_amdgcn_s_setprio(0);

        // ---- lane-local softmax (base-2, defer-max THR=11)
        float lm[2];
        #pragma unroll
        for (int m2 = 0; m2 < 2; ++m2) {
            float a0 = fmaxf(fmaxf(s[0][m2][0], s[0][m2][1]), fmaxf(s[0][m2][2], s[0][m2][3]));
            float a1 = fmaxf(fmaxf(s[1][m2][0], s[1][m2][1]), fmaxf(s[1][m2][2], s[1][m2][3]));
            lm[m2] = fmaxf(a0, a1);
        }
        int need = (lm[0] > mx[0] + 11.f) || (lm[1] > mx[1] + 11.f);
        if (__any(need)) {
            #pragma unroll
            for (int m2 = 0; m2 < 2; ++m2) {
                float v = lm[m2];
                v = fmaxf(v, __shfl_xor(v, 16));
                v = fmaxf(v, __shfl_xor(v, 32));
                float mn = fmaxf(mx[m2], v);
                float a  = exp2a(mx[m2] - mn);
                mx[m2] = mn;
                l[m2] *= a;
                #pragma unroll
                for (int cc = 0; cc < 8; ++cc) {
                    O[m2][cc][0] *= a; O[m2][cc][1] *= a;
                    O[m2][cc][2] *= a; O[m2][cc][3] *= a;
                }
            }
        }
        // P fragments in-register: slots 0-3 <- tt0 (keys lg*4+r), 4-7 <- tt1
        bf16x8 pb[2];
        #pragma unroll
        for (int m2 = 0; m2 < 2; ++m2) {
            float e[8];
            #pragma unroll
            for (int r = 0; r < 4; ++r) {
                e[r]     = exp2a(s[0][m2][r] - mx[m2]);
                e[4 + r] = exp2a(s[1][m2][r] - mx[m2]);
            }
            l[m2] += ((e[0] + e[1]) + (e[2] + e[3])) + ((e[4] + e[5]) + (e[6] + e[7]));
            #pragma unroll
            for (int i = 0; i < 8; ++i) pb[m2][i] = f2bf(e[i]);
        }

        // ---- O^T += V^T P^T : A = V-frag (same k-permutation), B = P
        __builtin_amdgcn_s_setprio(1);
        #pragma unroll
        for (int cc = 0; cc < 8; ++cc) {
            const short* vb = &V_lds[p][(cc * 16 + lr) * 40 + lg * 4];
            bf16x4 va0 = *(const bf16x4*)vb;         // keys lg*4 + 0..3
            bf16x4 va1 = *(const bf16x4*)(vb + 16);  // keys 16 + lg*4 + 0..3
            bf16x8 vf = __builtin_shufflevector(va0, va1, 0, 1, 2, 3, 4, 5, 6, 7);
            O[0][cc] = mfma16(vf, pb[0], O[0][cc]);
            O[1][cc] = mfma16(vf, pb[1], O[1][cc]);
        }
        __builtin_amdgcn_s_setprio(0);

        if (pre) writeV(p ^ 1);
        __syncthreads();
    }

    // ---- epilogue: reduce l across lg groups, write partial + lse2
    const size_t obase = (size_t)(ks * NB + n) * HW;
    #pragma unroll
    for (int m2 = 0; m2 < 2; ++m2) {
        float v = l[m2];
        v += __shfl_xor(v, 16);
        v += __shfl_xor(v, 32);
        l[m2] = v;
        const float inv = 1.f / v;
        const int q = q0 + m2 * 16 + lr;
        #pragma unroll
        for (int cc = 0; cc < 8; ++cc) {
            ushort4 ov;
            ov.x = (unsigned short)f2bf(O[m2][cc][0] * inv);
            ov.y = (unsigned short)f2bf(O[m2][cc][1] * inv);
            ov.z = (unsigned short)f2bf(O[m2][cc][2] * inv);
            ov.w = (unsigned short)f2bf(O[m2][cc][3] * inv);
            *(ushort4*)&Op[(obase + q) * ICH + cc * 16 + lg * 4] = ov;
        }
        if (lg == 0)
            Ls[obase + q] = mx[m2] + log2a(l[m2]);
    }
}

// ---------------------------------------------------------------------------
// K4: fused combine + final conv + residual.
// ---------------------------------------------------------------------------
__global__ __launch_bounds__(256) void k_out(const short* __restrict__ Op,
                                             const float* __restrict__ Ls,
                                             const short* __restrict__ wwb,
                                             const float* __restrict__ feat,
                                             float* __restrict__ out) {
    const int n    = blockIdx.y;
    const int wave = threadIdx.x >> 6;
    const int lane = threadIdx.x & 63;
    const int lr = lane & 15, lg = lane >> 4;
    const int q0 = blockIdx.x * 32;
    const int o0 = wave * 64;

    float w[2][KSPL];
    #pragma unroll
    for (int nf = 0; nf < 2; ++nf) {
        const int q = q0 + nf * 16 + lr;
        float ls[KSPL], M = -INFINITY;
        #pragma unroll
        for (int i = 0; i < KSPL; ++i) {
            ls[i] = Ls[((size_t)i * NB + n) * HW + q];
            M = fmaxf(M, ls[i]);
        }
        float ws = 0.f;
        #pragma unroll
        for (int i = 0; i < KSPL; ++i) { w[nf][i] = exp2a(ls[i] - M); ws += w[nf][i]; }
        float inv = 1.f / ws;
        #pragma unroll
        for (int i = 0; i < KSPL; ++i) w[nf][i] *= inv;
    }

    f32x4 acc[4][2];
    #pragma unroll
    for (int i = 0; i < 4; ++i)
        #pragma unroll
        for (int jn = 0; jn < 2; ++jn) { acc[i][jn][0]=0.f; acc[i][jn][1]=0.f; acc[i][jn][2]=0.f; acc[i][jn][3]=0.f; }

    #pragma unroll
    for (int cf = 0; cf < 4; ++cf) {
        bf16x8 bO[2];
        #pragma unroll
        for (int nf = 0; nf < 2; ++nf) {
            const size_t base = ((size_t)n * HW + q0 + nf * 16 + lr) * ICH + cf * 32 + lg * 8;
            float fo[8] = {0.f,0.f,0.f,0.f,0.f,0.f,0.f,0.f};
            #pragma unroll
            for (int i = 0; i < KSPL; ++i) {
                bf16x8 v = ldf(Op + (size_t)i * NB * HW * ICH + base);
                #pragma unroll
                for (int e = 0; e < 8; ++e) fo[e] += w[nf][i] * bf2f(v[e]);
            }
            #pragma unroll
            for (int e = 0; e < 8; ++e) bO[nf][e] = f2bf(fo[e]);
        }
        #pragma unroll
        for (int mf = 0; mf < 4; ++mf) {
            bf16x8 a = ldf(wwb + (o0 + mf * 16 + lr) * ICH + cf * 32 + lg * 8);
            #pragma unroll
            for (int nf = 0; nf < 2; ++nf)
                acc[mf][nf] = mfma16(a, bO[nf], acc[mf][nf]);
        }
    }
    #pragma unroll
    for (int mf = 0; mf < 4; ++mf) {
        #pragma unroll
        for (int nf = 0; nf < 2; ++nf) {
            #pragma unroll
            for (int r = 0; r < 4; ++r) {
                int o = o0 + mf * 16 + lg * 4 + r;
                int q = q0 + nf * 16 + lr;
                long long cxi = (((long long)(n * CIN + o)) * 9 + 5) * HW + q;
                out[((long long)(n * CIN + o)) * HW + q] = acc[mf][nf][r] + feat[cxi];
            }
        }
    }
}

// ---------------------------------------------------------------------------
extern "C" void kernel_launch(void* const* d_in, const int* in_sizes, int n_in,
                              void* d_out, int out_size, void* d_ws, size_t ws_size,
                              hipStream_t stream) {
    const float* feat = (const float*)d_in[0];
    const float* wth  = (const float*)d_in[1];
    const float* gth  = (const float*)d_in[2];
    const float* bth  = (const float*)d_in[3];
    const float* mth  = (const float*)d_in[4];
    const float* vth  = (const float*)d_in[5];
    const float* wph  = (const float*)d_in[6];
    const float* gph  = (const float*)d_in[7];
    const float* bph  = (const float*)d_in[8];
    const float* mph  = (const float*)d_in[9];
    const float* vph  = (const float*)d_in[10];
    const float* wg   = (const float*)d_in[11];
    const float* ww   = (const float*)d_in[12];
    float* out = (float*)d_out;

    size_t off = 0;
    auto carve = [&](size_t bytes) {
        void* p = (char*)d_ws + off;
        off += (bytes + 255) & ~(size_t)255;
        return p;
    };
    short* Xbf   = (short*)carve((size_t)NB * HW * CIN * 2);
    short* CXbf  = (short*)carve((size_t)NB * HW * CIN * 2);
    short* theta = (short*)carve((size_t)NB * HW * ICH * 2);
    short* phi   = (short*)carve((size_t)NB * HW * ICH * 2);
    short* Vt    = (short*)carve((size_t)NB * ICH * HW * 2);
    short* Op    = (short*)carve((size_t)KSPL * NB * HW * ICH * 2);
    float* Ls    = (float*)carve((size_t)KSPL * NB * HW * 4);
    short* wthb  = (short*)carve((size_t)ICH * CIN * 2);
    short* wphb  = (short*)carve((size_t)ICH * CIN * 2);
    short* wgb   = (short*)carve((size_t)ICH * CIN * 2);
    short* wwb   = (short*)carve((size_t)CIN * ICH * 2);
    float* bnp   = (float*)carve((size_t)4 * ICH * 4);

    k_prep_w<<<128, 256, 0, stream>>>(wth, wph, wg, ww, gth, bth, mth, vth,
                                      gph, bph, mph, vph, wthb, wphb, wgb, wwb, bnp);
    k_prep_x<<<dim3(64, 8, NB), 256, 0, stream>>>(feat, Xbf, CXbf);
    k_conv3<<<dim3(64, NB), 256, 0, stream>>>(Xbf, CXbf, wthb, wphb, wgb, bnp,
                                              theta, phi, Vt);
    k_attn<<<1024, 256, 0, stream>>>(theta, phi, Vt, Op, Ls);
    k_out<<<dim3(128, NB), 256, 0, stream>>>(Op, Ls, wwb, feat, out);
}